// Round 13
// baseline (411.534 us; speedup 1.0000x reference)
//
#include <hip/hip_runtime.h>

// ---------------------------------------------------------------------------
// Fused QKV-projection + attention (B=8, C=2048, N=512), fp32 in/out.
// Precision: fp32 -> fp16 hi/lo split. Projections: full 3-term fp16 MFMA.
// Attention logits: 1.5-term (S = qh*kh). Measured absmax 1.71e-3 vs 4.57e-3.
// Round 13: DUPLICATED-QK PAIR (R9 occupancy x R12 locality). R9 (200us) =
// 2 waves/SIMD but 2-barrier pair exchange; R12 (240us) = exchange-free but
// 1 wave/SIMD. v13: 8 waves/4 pairs, both waves of a pair compute the FULL
// S[16q][32kv] (32 QK MFMAs, whole K-tile read) -> softmax fully wave-local
// (deterministic-identical in both waves), P bounce in private LDS behind
// lgkmcnt-only fence, PV n-split (proven 128-VGPR + 128-AGPR envelope).
// ONE __syncthreads per tile. LDS kept ~93 KB -> 1 block/CU -> 256-reg budget.
// ---------------------------------------------------------------------------

typedef _Float16 half_t;
typedef __attribute__((ext_vector_type(8))) _Float16 half8;
typedef __attribute__((ext_vector_type(4))) _Float16 half4;
typedef __attribute__((ext_vector_type(4))) float    f32x4;

#define MFMA16x32(A_, B_, C_) __builtin_amdgcn_mfma_f32_16x16x32_f16((A_), (B_), (C_), 0, 0, 0)

// wave-local LDS write->read fence (same wave): order + drain, no barrier.
#define LDS_FENCE() asm volatile("s_waitcnt lgkmcnt(0)" ::: "memory")

__device__ __forceinline__ void gload_lds16(const void* g, void* l) {
  __builtin_amdgcn_global_load_lds(
      (const __attribute__((address_space(1))) void*)g,
      (__attribute__((address_space(3))) void*)l, 16, 0, 0);
}

// max-reduce over each 16-lane row via DPP (quad_perm xor1/xor2, row_ror 4/8).
__device__ __forceinline__ float dpp_max16(float x) {
  int t;
  t = __builtin_amdgcn_update_dpp(__float_as_int(x), __float_as_int(x), 0xB1, 0xF, 0xF, false);
  x = fmaxf(x, __int_as_float(t));
  t = __builtin_amdgcn_update_dpp(__float_as_int(x), __float_as_int(x), 0x4E, 0xF, 0xF, false);
  x = fmaxf(x, __int_as_float(t));
  t = __builtin_amdgcn_update_dpp(__float_as_int(x), __float_as_int(x), 0x124, 0xF, 0xF, false);
  x = fmaxf(x, __int_as_float(t));
  t = __builtin_amdgcn_update_dpp(__float_as_int(x), __float_as_int(x), 0x128, 0xF, 0xF, false);
  x = fmaxf(x, __int_as_float(t));
  return x;
}

// ---- split fp32 [rows][cols] -> fp16 [rows][2*cols] = [hi | lo] -------------
__global__ void split_hilo(const float* __restrict__ src, half_t* __restrict__ dst,
                           int rows, int cols) {
  int idx = blockIdx.x * 256 + threadIdx.x;
  int total = rows * cols / 4;
  if (idx >= total) return;
  f32x4 v = ((const f32x4*)src)[idx];
  int e = idx * 4;
  int r = e / cols, c = e % cols;
  half4 h, l;
#pragma unroll
  for (int j = 0; j < 4; ++j) {
    float f = v[j];
    _Float16 hh = (_Float16)f;
    h[j] = hh;
    l[j] = (_Float16)(f - (float)hh);
  }
  *(half4*)&dst[(size_t)r * (2 * cols) + c] = h;
  *(half4*)&dst[(size_t)r * (2 * cols) + c + cols] = l;
}

// ---- projection GEMM (unchanged) ---------------------------------------------
// MODE 2: out[t*512 + m] = f16(val)                       (q/k, hi-only compact)
// MODE 1: out[(t>>5)*16384 + m*32 + (t&31)] = f16(val)    (v kv-blocked)
template <int MODE>
__global__ __launch_bounds__(256) void proj_gemm(
    const half_t* __restrict__ A, const half_t* __restrict__ Bm,
    const float* __restrict__ bias, half_t* __restrict__ out) {
  __shared__ half_t At[128 * 64];
  __shared__ half_t Bt[128 * 64];
  const int tid = threadIdx.x;
  const int lane = tid & 63, wv = tid >> 6;
  const int g = lane >> 4, li = lane & 15;
  const int wm = wv >> 1, wn = wv & 1;
  const int M0 = blockIdx.x * 128, N0 = blockIdx.y * 128;

  const f32x4 kZero = {0.f, 0.f, 0.f, 0.f};
  f32x4 acc[4][4];
#pragma unroll
  for (int i = 0; i < 4; ++i)
#pragma unroll
    for (int j = 0; j < 4; ++j) acc[i][j] = kZero;

  for (int kt = 0; kt < 24; ++kt) {
    const int kc = kt * 64;
    const int ab = kc & 1023;
    const int bb = (kc < 512) ? kc : (kc - 512);
    __syncthreads();
#pragma unroll
    for (int s2 = 0; s2 < 4; ++s2) {
      int bid = tid + 256 * s2;
      int row = bid >> 3, blk = bid & 7;
      half8 va = *(const half8*)&A[(size_t)(M0 + row) * 1024 + ab + blk * 8];
      *(half8*)&At[row * 64 + ((blk ^ (row & 7)) * 8)] = va;
      half8 vb = *(const half8*)&Bm[(size_t)(N0 + row) * 1024 + bb + blk * 8];
      *(half8*)&Bt[row * 64 + ((blk ^ (row & 7)) * 8)] = vb;
    }
    __syncthreads();
#pragma unroll
    for (int kk = 0; kk < 2; ++kk) {
      half8 af[4], bf[4];
#pragma unroll
      for (int i = 0; i < 4; ++i) {
        int ar = wm * 64 + i * 16 + li;
        af[i] = *(const half8*)&At[ar * 64 + (((4 * kk + g) ^ (ar & 7)) * 8)];
        int br = wn * 64 + i * 16 + li;
        bf[i] = *(const half8*)&Bt[br * 64 + (((4 * kk + g) ^ (br & 7)) * 8)];
      }
#pragma unroll
      for (int i = 0; i < 4; ++i)
#pragma unroll
        for (int j = 0; j < 4; ++j) acc[i][j] = MFMA16x32(af[i], bf[j], acc[i][j]);
    }
  }

  if (MODE == 2) {
#pragma unroll
    for (int i = 0; i < 4; ++i) {
      int trow = M0 + wm * 64 + i * 16 + 4 * g;
#pragma unroll
      for (int j = 0; j < 4; ++j) {
        int m = N0 + wn * 64 + j * 16 + li;
        float bs = bias[m];
#pragma unroll
        for (int r = 0; r < 4; ++r) {
          out[(size_t)(trow + r) * 512 + m] = (_Float16)(acc[i][j][r] + bs);
        }
      }
    }
  } else {
#pragma unroll
    for (int i = 0; i < 4; ++i) {
      int m0r = M0 + wm * 64 + i * 16 + 4 * g;
#pragma unroll
      for (int r = 0; r < 4; ++r) {
        int m = m0r + r;
        float bs = bias[m];
#pragma unroll
        for (int j = 0; j < 4; ++j) {
          int tt = N0 + wn * 64 + j * 16 + li;
          out[(size_t)(tt >> 5) * 16384 + (size_t)m * 32 + (tt & 31)] =
              (_Float16)(acc[i][j][r] + bs);
        }
      }
    }
  }
}

// ---- flash attention v13 ----------------------------------------------------
// grid 256 (1 block/CU), 512 threads = 8 waves = 4 pairs x 16 q-rows.
// Both waves of a pair compute full S[16q][32kv] (QK duplicated); softmax is
// wave-local (identical in both); PV n-split (wbit half). One barrier/tile.
__global__ __attribute__((amdgpu_flat_work_group_size(512, 512),
                          amdgpu_waves_per_eu(2, 2))) void flash_attn(
    const half_t* __restrict__ qs, const half_t* __restrict__ ks,
    const half_t* __restrict__ vblk, float* __restrict__ outp) {
  __shared__ half_t kt[2][20480];      // 2 x 40 KB declared (32 KB used each):
                                       // keeps 1 block/CU -> 256-reg budget
  __shared__ half_t plds[8][16][40];   // P per WAVE [q16][kv32+pad] (80B rows)
  __shared__ float  tmw[8][16];        // per-wave row-max relay (li layout)
  __shared__ float  lx[8][16];         // per-wave l relay

  const int blk0 = blockIdx.x;
  const int logical = (blk0 & 7) * 32 + (blk0 >> 3);   // XCD-chunked (256%8==0)
  const int b  = logical >> 5;                         // batch = XCD
  const int c0 = (logical & 31) * 64;
  const int tid = threadIdx.x;
  const int wv = tid >> 6, lane = tid & 63;
  const int pair = wv >> 1, wbit = wv & 1;
  const int g = lane >> 4, li = lane & 15;
  const int qr0 = c0 + pair * 16;
  const int nh0 = wbit * 256;          // this wave's n-half for PV/output

  const char* kbytes = (const char*)(ks + (size_t)b * 2048 * 512);

  // Q-hi fragments pinned in registers (volatile asm: loaded exactly once):
  const half_t* qrow = qs + (size_t)(b * 2048 + qr0 + li) * 512 + 8 * g;
  half8 qh[16];
#pragma unroll
  for (int c = 0; c < 16; ++c) {
    const half_t* ah = qrow + c * 32;
    asm volatile("global_load_dwordx4 %0, %1, off" : "=v"(qh[c]) : "v"(ah));
  }
  asm volatile("s_waitcnt vmcnt(0)" ::: "memory");

  const f32x4 kZero = {0.f, 0.f, 0.f, 0.f};
  f32x4 o[16];                          // n-half accumulators (64 AGPR)
#pragma unroll
  for (int i = 0; i < 16; ++i) o[i] = kZero;
  float mr[4] = {-3e38f, -3e38f, -3e38f, -3e38f};  // running max, rows 4g+r
  float m_li = -3e38f, l_li = 0.f;                 // running max/l, row li

  // stage K-hi tile: 32 rows x 1024 B = 2048 16B-segs, 4 per thread.
  auto STAGE = [&](int kv0s, int bufs) {
#pragma unroll
    for (int i2 = 0; i2 < 4; ++i2) {
      int seg = i2 * 512 + tid;
      int r = seg >> 6, bb = seg & 63;
      int bsrc = bb ^ (r & 7);
      gload_lds16(kbytes + (size_t)(kv0s + r) * 1024 + bsrc * 16,
                  (void*)&kt[bufs][seg * 8]);
    }
  };

  STAGE(0, 0);
  __syncthreads();
  int cur = 0;

#pragma unroll 1
  for (int t = 0; t < 64; ++t) {
    // ---- V prefetch for THIS tile (plain loads; compiler schedules) ----
    const half_t* vtile = vblk + ((size_t)(b * 64 + t)) * 16384 +
                          (size_t)nh0 * 32 + li * 32 + 8 * g;
    half8 vreg[16];
#pragma unroll
    for (int ns = 0; ns < 16; ++ns) vreg[ns] = *(const half8*)(vtile + ns * 512);

    if (t + 1 < 64) STAGE((t + 1) * 32, cur ^ 1);   // prefetch next K tile

    // ---- QK: FULL S[16q][32kv] per wave (duplicated across the pair) ----
    const half_t* krow0 = &kt[cur][(size_t)li * 512];
    const half_t* krow1 = &kt[cur][(size_t)(16 + li) * 512];
    const int swz = li & 7;
    f32x4 s0A = kZero, s0B = kZero, s1A = kZero, s1B = kZero;
#pragma unroll
    for (int c = 0; c < 16; c += 2) {
      int of0 = ((4 * c + g) ^ swz) * 8;
      int of1 = ((4 * c + 4 + g) ^ swz) * 8;
      half8 k00 = *(const half8*)&krow0[of0];
      half8 k10 = *(const half8*)&krow1[of0];
      half8 k01 = *(const half8*)&krow0[of1];
      half8 k11 = *(const half8*)&krow1[of1];
      s0A = MFMA16x32(qh[c], k00, s0A);
      s1A = MFMA16x32(qh[c], k10, s1A);
      s0B = MFMA16x32(qh[c + 1], k01, s0B);
      s1B = MFMA16x32(qh[c + 1], k11, s1B);
    }
    f32x4 sv0 = s0A + s0B;               // cols li
    f32x4 sv1 = s1A + s1B;               // cols 16+li

    // ---- full-row max, wave-local (identical across the pair) ----
    float tm[4];
#pragma unroll
    for (int r = 0; r < 4; ++r)
      tm[r] = fmaxf(dpp_max16(sv0[r]), dpp_max16(sv1[r]));

    // ---- P = exp(S - tm) <= 1 -> private LDS buffer; relay tm to li layout
#pragma unroll
    for (int r = 0; r < 4; ++r) {
      float p0 = __expf(sv0[r] - tm[r]);
      float p1 = __expf(sv1[r] - tm[r]);
      plds[wv][4 * g + r][li] = (half_t)p0;
      plds[wv][4 * g + r][li + 16] = (half_t)p1;
    }
    if (li == 0) {
#pragma unroll
      for (int r = 0; r < 4; ++r) tmw[wv][4 * g + r] = tm[r];
    }
    LDS_FENCE();   // wave-local write->read ordering; NO barrier

    // ---- defer-max (THR=8): rescale o only when a row max jumps ----
    int grow = (tm[0] > mr[0] + 8.f) | (tm[1] > mr[1] + 8.f) |
               (tm[2] > mr[2] + 8.f) | (tm[3] > mr[3] + 8.f);
    float tli = tmw[wv][li];
    if (__any(grow)) {
      float al[4];
#pragma unroll
      for (int r = 0; r < 4; ++r) {
        float mn = fmaxf(mr[r], tm[r]);
        al[r] = __expf(mr[r] - mn);
        mr[r] = mn;
      }
      f32x4 av = {al[0], al[1], al[2], al[3]};
#pragma unroll
      for (int i = 0; i < 16; ++i) o[i] *= av;
      float mnli = fmaxf(m_li, tli);
      l_li *= __expf(m_li - mnli);
      m_li = mnli;
    }

    // pa = P row li, scaled by exp(tli - m_li) <= e^8 (defer bound)
    float sh = __expf(tli - m_li);
    half_t sh16 = (half_t)sh;
    half8 pa = *(const half8*)&plds[wv][li][8 * g];
#pragma unroll
    for (int e = 0; e < 8; ++e) pa[e] = pa[e] * sh16;

    // l harvested from the scaled pa fragment (xor16/32 sums the 4 g-groups)
    float lp = 0.f;
#pragma unroll
    for (int e = 0; e < 8; ++e) lp += (float)pa[e];
    lp += __shfl_xor(lp, 16);
    lp += __shfl_xor(lp, 32);
    l_li += lp;

    // ---- PV over this wave's n-half from prefetched V registers ----
#pragma unroll
    for (int ns = 0; ns < 16; ++ns) {
      o[ns] = MFMA16x32(pa, vreg[ns], o[ns]);
    }

    __syncthreads();   // the ONE barrier: drain stage (vmcnt0), protect kt
    cur ^= 1;
  }

  // ---- final normalization (wave-local relay li -> 4g+r layout) ----
  if (g == 0) lx[wv][li] = l_li;
  LDS_FENCE();
  float inv[4];
#pragma unroll
  for (int r = 0; r < 4; ++r) inv[r] = 1.0f / (lx[wv][4 * g + r] * 22.62741699796952f);

  float* ob = outp + (size_t)b * 1048576 + qr0 + 4 * g;
#pragma unroll
  for (int ns = 0; ns < 16; ++ns) {
#pragma unroll
    for (int r = 0; r < 4; ++r) {
      ob[(size_t)(nh0 + ns * 16 + li) * 2048 + r] = o[ns][r] * inv[r];
    }
  }
}

// ---------------------------------------------------------------------------
extern "C" void kernel_launch(void* const* d_in, const int* in_sizes, int n_in,
                              void* d_out, int out_size, void* d_ws, size_t ws_size,
                              hipStream_t stream) {
  const float* x  = (const float*)d_in[0];
  const float* Wq = (const float*)d_in[1];
  const float* bq = (const float*)d_in[2];
  const float* Wk = (const float*)d_in[3];
  const float* bk = (const float*)d_in[4];
  const float* Wv = (const float*)d_in[5];
  const float* bv = (const float*)d_in[6];

  half_t* xs  = (half_t*)d_ws;                  // [16384][1024] hi|lo
  half_t* qsb = xs  + (size_t)16384 * 1024;     // [16384][512]  hi only
  half_t* ksb = qsb + (size_t)16384 * 512;      // [16384][512]  hi only
  half_t* vtb = ksb + (size_t)16384 * 512;      // [512 blk][512 n][32 kv]
  half_t* wqs = vtb + (size_t)512 * 16384;      // [512][1024]
  half_t* wks = wqs + (size_t)512 * 1024;
  half_t* wvs = wks + (size_t)512 * 1024;

  split_hilo<<<dim3(16384 * 512 / 4 / 256), 256, 0, stream>>>(x, xs, 16384, 512);
  split_hilo<<<dim3(512 * 512 / 4 / 256), 256, 0, stream>>>(Wq, wqs, 512, 512);
  split_hilo<<<dim3(512 * 512 / 4 / 256), 256, 0, stream>>>(Wk, wks, 512, 512);
  split_hilo<<<dim3(512 * 512 / 4 / 256), 256, 0, stream>>>(Wv, wvs, 512, 512);

  proj_gemm<2><<<dim3(128, 4), 256, 0, stream>>>(xs, wqs, bq, qsb);
  proj_gemm<2><<<dim3(128, 4), 256, 0, stream>>>(xs, wks, bk, ksb);
  proj_gemm<1><<<dim3(4, 128), 256, 0, stream>>>(wvs, xs, bv, vtb);

  flash_attn<<<dim3(256), 512, 0, stream>>>(qsb, ksb, vtb, (float*)d_out);
}

// Round 14
// 246.964 us; speedup vs baseline: 1.6664x; 1.6664x over previous
//
#include <hip/hip_runtime.h>

// ---------------------------------------------------------------------------
// Fused QKV-projection + attention (B=8, C=2048, N=512), fp32 in/out.
// Round 14: FLASH = R9 VERBATIM (200us, the proven local optimum of the
// 128-VGPR+128-AGPR envelope; R10/R11/R13 all spilled and lost). Side-kernel
// diet instead: projections hi*hi-only (K=512 instead of 1536 ext — q/k/v are
// fp16-stored anyway, so proj precision was overkill; ledger-predicted absmax
// ~2.5e-3 vs threshold 4.57e-3), splits become plain fp32->fp16 casts.
// ---------------------------------------------------------------------------

typedef _Float16 half_t;
typedef __attribute__((ext_vector_type(8))) _Float16 half8;
typedef __attribute__((ext_vector_type(4))) _Float16 half4;
typedef __attribute__((ext_vector_type(4))) float    f32x4;

#define MFMA16x32(A_, B_, C_) __builtin_amdgcn_mfma_f32_16x16x32_f16((A_), (B_), (C_), 0, 0, 0)

// barrier that is ALSO a compiler memory fence, without draining vmcnt:
#define LIGHT_BARRIER() asm volatile("s_waitcnt lgkmcnt(0)\n\ts_barrier" ::: "memory")

__device__ __forceinline__ void gload_lds16(const void* g, void* l) {
  __builtin_amdgcn_global_load_lds(
      (const __attribute__((address_space(1))) void*)g,
      (__attribute__((address_space(3))) void*)l, 16, 0, 0);
}

// max-reduce over each 16-lane row via DPP (quad_perm xor1/xor2, row_ror 4/8).
__device__ __forceinline__ float dpp_max16(float x) {
  int t;
  t = __builtin_amdgcn_update_dpp(__float_as_int(x), __float_as_int(x), 0xB1, 0xF, 0xF, false);
  x = fmaxf(x, __int_as_float(t));
  t = __builtin_amdgcn_update_dpp(__float_as_int(x), __float_as_int(x), 0x4E, 0xF, 0xF, false);
  x = fmaxf(x, __int_as_float(t));
  t = __builtin_amdgcn_update_dpp(__float_as_int(x), __float_as_int(x), 0x124, 0xF, 0xF, false);
  x = fmaxf(x, __int_as_float(t));
  t = __builtin_amdgcn_update_dpp(__float_as_int(x), __float_as_int(x), 0x128, 0xF, 0xF, false);
  x = fmaxf(x, __int_as_float(t));
  return x;
}

// ---- plain cast fp32 -> fp16 (hi only) --------------------------------------
__global__ void cast_f16(const float* __restrict__ src, half_t* __restrict__ dst,
                         int total4) {
  int idx = blockIdx.x * 256 + threadIdx.x;
  if (idx >= total4) return;
  f32x4 v = ((const f32x4*)src)[idx];
  half4 h;
#pragma unroll
  for (int j = 0; j < 4; ++j) h[j] = (_Float16)v[j];
  *(half4*)&dst[(size_t)idx * 4] = h;
}

// ---- projection GEMM, hi*hi only: C[M][512] = A[M][512] . B[512][512]^T -----
// MODE 2: out[t*512 + m] = f16(val)                       (q/k compact)
// MODE 1: out[(t>>5)*16384 + m*32 + (t&31)] = f16(val)    (v kv-blocked)
template <int MODE>
__global__ __launch_bounds__(256) void proj_gemm(
    const half_t* __restrict__ A, const half_t* __restrict__ Bm,
    const float* __restrict__ bias, half_t* __restrict__ out) {
  __shared__ half_t At[128 * 64];
  __shared__ half_t Bt[128 * 64];
  const int tid = threadIdx.x;
  const int lane = tid & 63, wv = tid >> 6;
  const int g = lane >> 4, li = lane & 15;
  const int wm = wv >> 1, wn = wv & 1;
  const int M0 = blockIdx.x * 128, N0 = blockIdx.y * 128;

  const f32x4 kZero = {0.f, 0.f, 0.f, 0.f};
  f32x4 acc[4][4];
#pragma unroll
  for (int i = 0; i < 4; ++i)
#pragma unroll
    for (int j = 0; j < 4; ++j) acc[i][j] = kZero;

  for (int kt = 0; kt < 8; ++kt) {      // K = 512, 8 tiles of 64
    const int kc = kt * 64;
    __syncthreads();
#pragma unroll
    for (int s2 = 0; s2 < 4; ++s2) {
      int bid = tid + 256 * s2;
      int row = bid >> 3, blk = bid & 7;
      half8 va = *(const half8*)&A[(size_t)(M0 + row) * 512 + kc + blk * 8];
      *(half8*)&At[row * 64 + ((blk ^ (row & 7)) * 8)] = va;
      half8 vb = *(const half8*)&Bm[(size_t)(N0 + row) * 512 + kc + blk * 8];
      *(half8*)&Bt[row * 64 + ((blk ^ (row & 7)) * 8)] = vb;
    }
    __syncthreads();
#pragma unroll
    for (int kk = 0; kk < 2; ++kk) {
      half8 af[4], bf[4];
#pragma unroll
      for (int i = 0; i < 4; ++i) {
        int ar = wm * 64 + i * 16 + li;
        af[i] = *(const half8*)&At[ar * 64 + (((4 * kk + g) ^ (ar & 7)) * 8)];
        int br = wn * 64 + i * 16 + li;
        bf[i] = *(const half8*)&Bt[br * 64 + (((4 * kk + g) ^ (br & 7)) * 8)];
      }
#pragma unroll
      for (int i = 0; i < 4; ++i)
#pragma unroll
        for (int j = 0; j < 4; ++j) acc[i][j] = MFMA16x32(af[i], bf[j], acc[i][j]);
    }
  }

  if (MODE == 2) {
#pragma unroll
    for (int i = 0; i < 4; ++i) {
      int trow = M0 + wm * 64 + i * 16 + 4 * g;
#pragma unroll
      for (int j = 0; j < 4; ++j) {
        int m = N0 + wn * 64 + j * 16 + li;
        float bs = bias[m];
#pragma unroll
        for (int r = 0; r < 4; ++r) {
          out[(size_t)(trow + r) * 512 + m] = (_Float16)(acc[i][j][r] + bs);
        }
      }
    }
  } else {
#pragma unroll
    for (int i = 0; i < 4; ++i) {
      int m0r = M0 + wm * 64 + i * 16 + 4 * g;
#pragma unroll
      for (int r = 0; r < 4; ++r) {
        int m = m0r + r;
        float bs = bias[m];
#pragma unroll
        for (int j = 0; j < 4; ++j) {
          int tt = N0 + wn * 64 + j * 16 + li;
          out[(size_t)(tt >> 5) * 16384 + (size_t)m * 32 + (tt & 31)] =
              (_Float16)(acc[i][j][r] + bs);
        }
      }
    }
  }
}

// ---- flash attention (R9 verbatim — the proven 200us kernel) ----------------
// grid 256 (1 block/CU), 512 threads = 8 waves = 4 pair-groups x 16 q-rows.
// Wave pair: wbit splits kv (QK) and n (PV). K-hi tile double-buffered via
// global_load_lds. Q-hi register-resident (64 VGPR); V prefetched into regs
// at tile top. LDS >80KB keeps 1 block/CU -> 256-total register budget.
__global__ __attribute__((amdgpu_flat_work_group_size(512, 512),
                          amdgpu_waves_per_eu(2, 2))) void flash_attn(
    const half_t* __restrict__ qs, const half_t* __restrict__ ks,
    const half_t* __restrict__ vblk, float* __restrict__ outp) {
  __shared__ half_t kt[2][20480];      // 2 x 40 KB declared (32 KB used each)
  __shared__ half_t plds[4][16][40];   // P per pair-group [q16][kv32+pad16B]
  __shared__ float  tmx[4][2][16];     // per-tile half row-max [grp][wbit][row]
  __shared__ float  lx[4][16];         // final l exchange [grp][row]

  const int blk0 = blockIdx.x;
  const int logical = (blk0 & 7) * 32 + (blk0 >> 3);   // XCD-chunked (256%8==0)
  const int b  = logical >> 5;                         // batch = XCD
  const int c0 = (logical & 31) * 64;
  const int tid = threadIdx.x;
  const int wv = tid >> 6, lane = tid & 63;
  const int grp = wv >> 1, wbit = wv & 1;
  const int g = lane >> 4, li = lane & 15;
  const int qr0 = c0 + grp * 16;
  const int nh0 = wbit * 256;          // this wave's n-half for PV/output

  const char* kbytes = (const char*)(ks + (size_t)b * 2048 * 512);

  // Q-hi fragments pinned in registers (volatile asm: loaded exactly once):
  const half_t* qrow = qs + (size_t)(b * 2048 + qr0 + li) * 512 + 8 * g;
  half8 qh[16];
#pragma unroll
  for (int c = 0; c < 16; ++c) {
    const half_t* ah = qrow + c * 32;
    asm volatile("global_load_dwordx4 %0, %1, off" : "=v"(qh[c]) : "v"(ah));
  }
  asm volatile("s_waitcnt vmcnt(0)" ::: "memory");

  const f32x4 kZero = {0.f, 0.f, 0.f, 0.f};
  f32x4 o[16];
#pragma unroll
  for (int i = 0; i < 16; ++i) o[i] = kZero;
  float mr[4] = {-3e38f, -3e38f, -3e38f, -3e38f};  // joint running max, rows 4g+r
  float m_li = -3e38f, l_li = 0.f;                 // joint running max/l, row li

  // stage K-hi tile: 32 rows x 1024 B (contiguous) = 2048 16B-segs, 4/thread.
  auto STAGE = [&](int kv0s, int bufs) {
#pragma unroll
    for (int i2 = 0; i2 < 4; ++i2) {
      int seg = i2 * 512 + tid;
      int r = seg >> 6, bb = seg & 63;
      int bsrc = bb ^ (r & 7);
      gload_lds16(kbytes + (size_t)(kv0s + r) * 1024 + bsrc * 16,
                  (void*)&kt[bufs][seg * 8]);
    }
  };

  STAGE(0, 0);
  __syncthreads();
  int cur = 0;

#pragma unroll 1
  for (int t = 0; t < 64; ++t) {
    // ---- V prefetch for THIS tile (plain loads; compiler schedules) ----
    const half_t* vtile = vblk + ((size_t)(b * 64 + t)) * 16384 +
                          (size_t)nh0 * 32 + li * 32 + 8 * g;
    half8 vreg[16];
#pragma unroll
    for (int ns = 0; ns < 16; ++ns) vreg[ns] = *(const half8*)(vtile + ns * 512);

    if (t + 1 < 64) STAGE((t + 1) * 32, cur ^ 1);   // prefetch next K tile

    // ---- QK: S[16q][16kv(this wave)] = qh . kh^T, 2 MFMA chains ----
    const half_t* krow = &kt[cur][(wbit * 16 + li) * 512];
    const int swz = li & 7;
    f32x4 sA = kZero, sB = kZero;
#pragma unroll
    for (int c = 0; c < 16; c += 2) {
      half8 k0 = *(const half8*)&krow[((4 * c + g) ^ swz) * 8];
      half8 k1 = *(const half8*)&krow[((4 * c + 4 + g) ^ swz) * 8];
      sA = MFMA16x32(qh[c], k0, sA);
      sB = MFMA16x32(qh[c + 1], k1, sB);
    }
    f32x4 sv = sA + sB;

    // ---- per-row max of THIS half (DPP, pure VALU); P normalized by it ----
    float tm[4];
#pragma unroll
    for (int r = 0; r < 4; ++r) tm[r] = dpp_max16(sv[r]);
#pragma unroll
    for (int r = 0; r < 4; ++r) {
      float p = __expf(sv[r] - tm[r]);            // <= 1
      plds[grp][4 * g + r][li + 16 * wbit] = (half_t)p;
    }
    if (li == 0) {
#pragma unroll
      for (int r = 0; r < 4; ++r) tmx[grp][wbit][4 * g + r] = tm[r];
    }
    LIGHT_BARRIER();   // single exchange point: P + half-maxes visible

    // ---- joint max, defer-max (THR=8), pa rescale ----
    f32x4 t0 = *(const f32x4*)&tmx[grp][0][4 * g];
    f32x4 t1 = *(const f32x4*)&tmx[grp][1][4 * g];
    float tA = tmx[grp][0][li], tB = tmx[grp][1][li];
    float tf[4];
#pragma unroll
    for (int r = 0; r < 4; ++r) tf[r] = fmaxf(t0[r], t1[r]);
    int grow = (tf[0] > mr[0] + 8.f) | (tf[1] > mr[1] + 8.f) |
               (tf[2] > mr[2] + 8.f) | (tf[3] > mr[3] + 8.f);
    if (__any(grow)) {
      float al[4];
#pragma unroll
      for (int r = 0; r < 4; ++r) {
        float mn = fmaxf(mr[r], tf[r]);
        al[r] = __expf(mr[r] - mn);
        mr[r] = mn;
      }
      f32x4 av = {al[0], al[1], al[2], al[3]};
#pragma unroll
      for (int i = 0; i < 16; ++i) o[i] *= av;
      float mnli = fmaxf(m_li, fmaxf(tA, tB));
      l_li *= __expf(m_li - mnli);
      m_li = mnli;
    }
    // scale for this lane's pa fragment (cols 8g..8g+7 live in half g>>1):
    float sh = __expf(((g < 2) ? tA : tB) - m_li);   // <= e^8 (defer bound)
    half_t sh16 = (half_t)sh;
    half8 pa = *(const half8*)&plds[grp][li][8 * g];
#pragma unroll
    for (int e = 0; e < 8; ++e) pa[e] = pa[e] * sh16;

    // l harvested from the scaled pa fragment
    float lp = 0.f;
#pragma unroll
    for (int e = 0; e < 8; ++e) lp += (float)pa[e];
    lp += __shfl_xor(lp, 16);
    lp += __shfl_xor(lp, 32);
    l_li += lp;

    // ---- PV from prefetched V registers ----
#pragma unroll
    for (int ns = 0; ns < 16; ++ns) {
      o[ns] = MFMA16x32(pa, vreg[ns], o[ns]);
    }

    __syncthreads();   // full fence: drain stage (vmcnt0), protect kt/plds/tmx
    cur ^= 1;
  }

  // ---- final normalization: l in li-layout, o rows are 4g+r ----
  if (wbit == 0 && g == 0) lx[grp][li] = l_li;
  __syncthreads();
  float inv[4];
#pragma unroll
  for (int r = 0; r < 4; ++r) inv[r] = 1.0f / (lx[grp][4 * g + r] * 22.62741699796952f);

  float* ob = outp + (size_t)b * 1048576 + qr0 + 4 * g;
#pragma unroll
  for (int ns = 0; ns < 16; ++ns) {
#pragma unroll
    for (int r = 0; r < 4; ++r) {
      ob[(size_t)(nh0 + ns * 16 + li) * 2048 + r] = o[ns][r] * inv[r];
    }
  }
}

// ---------------------------------------------------------------------------
extern "C" void kernel_launch(void* const* d_in, const int* in_sizes, int n_in,
                              void* d_out, int out_size, void* d_ws, size_t ws_size,
                              hipStream_t stream) {
  const float* x  = (const float*)d_in[0];
  const float* Wq = (const float*)d_in[1];
  const float* bq = (const float*)d_in[2];
  const float* Wk = (const float*)d_in[3];
  const float* bk = (const float*)d_in[4];
  const float* Wv = (const float*)d_in[5];
  const float* bv = (const float*)d_in[6];

  half_t* xh  = (half_t*)d_ws;                  // [16384][512]
  half_t* qsb = xh  + (size_t)16384 * 512;      // [16384][512]
  half_t* ksb = qsb + (size_t)16384 * 512;      // [16384][512]
  half_t* vtb = ksb + (size_t)16384 * 512;      // [512 blk][512 n][32 kv]
  half_t* wqh = vtb + (size_t)16384 * 512;      // [512][512]
  half_t* wkh = wqh + (size_t)512 * 512;
  half_t* wvh = wkh + (size_t)512 * 512;

  cast_f16<<<dim3(16384 * 512 / 4 / 256), 256, 0, stream>>>(x, xh, 16384 * 512 / 4);
  cast_f16<<<dim3(512 * 512 / 4 / 256), 256, 0, stream>>>(Wq, wqh, 512 * 512 / 4);
  cast_f16<<<dim3(512 * 512 / 4 / 256), 256, 0, stream>>>(Wk, wkh, 512 * 512 / 4);
  cast_f16<<<dim3(512 * 512 / 4 / 256), 256, 0, stream>>>(Wv, wvh, 512 * 512 / 4);

  proj_gemm<2><<<dim3(128, 4), 256, 0, stream>>>(xh, wqh, bq, qsb);
  proj_gemm<2><<<dim3(128, 4), 256, 0, stream>>>(xh, wkh, bk, ksb);
  proj_gemm<1><<<dim3(4, 128), 256, 0, stream>>>(wvh, xh, bv, vtb);

  flash_attn<<<dim3(256), 512, 0, stream>>>(qsb, ksb, vtb, (float*)d_out);
}

// Round 15
// 243.889 us; speedup vs baseline: 1.6874x; 1.0126x over previous
//
#include <hip/hip_runtime.h>

// ---------------------------------------------------------------------------
// Fused QKV-projection + attention (B=8, C=2048, N=512), fp32 in/out.
// Round 15: MATERIALIZED-S restructure. Flash (200us) was latency-bound on a
// serial per-tile chain and structurally immovable (R10-R13 all lost to the
// 128-VGPR envelope). Replace it with throughput-shaped kernels, 2 c-chunks
// of 1024 rows/batch (S chunk = 67 MB fp32, L3-resident, overlays dead xh/W
// region -> ws ~116 MB < proven 120): s_gemm (S=q.k^T fp32) -> softmax_rows
// (wave/row exact max, P=exp(s-m) fp16 in-place, l->lbuf) -> pv_gemm
// (O=P.V, K=2048, 1/(l*sqrt512) + transposed scatter in epilogue).
// Precision identical to R14's measured absmax 3.36e-3 (hi-only S, fp16 P/V);
// exact-max softmax is slightly better than defer-max.
// ---------------------------------------------------------------------------

typedef _Float16 half_t;
typedef __attribute__((ext_vector_type(8))) _Float16 half8;
typedef __attribute__((ext_vector_type(4))) _Float16 half4;
typedef __attribute__((ext_vector_type(4))) float    f32x4;

#define MFMA16x32(A_, B_, C_) __builtin_amdgcn_mfma_f32_16x16x32_f16((A_), (B_), (C_), 0, 0, 0)

// ---- plain cast fp32 -> fp16 ------------------------------------------------
__global__ void cast_f16(const float* __restrict__ src, half_t* __restrict__ dst,
                         int total4) {
  int idx = blockIdx.x * 256 + threadIdx.x;
  if (idx >= total4) return;
  f32x4 v = ((const f32x4*)src)[idx];
  half4 h;
#pragma unroll
  for (int j = 0; j < 4; ++j) h[j] = (_Float16)v[j];
  *(half4*)&dst[(size_t)idx * 4] = h;
}

// ---- projection GEMM: C[M][512] = A[M][512] . B[512][512]^T + bias ----------
// MODE 2: out[t*512 + m] = f16(val)     (q/k compact; A=x tokens, B=W)
// MODE 1: out[m*16384 + t] = f16(val)   (v transposed;  A=Wv,     B=x)
template <int MODE>
__global__ __launch_bounds__(256) void proj_gemm(
    const half_t* __restrict__ A, const half_t* __restrict__ Bm,
    const float* __restrict__ bias, half_t* __restrict__ out) {
  __shared__ half_t At[128 * 64];
  __shared__ half_t Bt[128 * 64];
  const int tid = threadIdx.x;
  const int lane = tid & 63, wv = tid >> 6;
  const int g = lane >> 4, li = lane & 15;
  const int wm = wv >> 1, wn = wv & 1;
  const int M0 = blockIdx.x * 128, N0 = blockIdx.y * 128;

  const f32x4 kZero = {0.f, 0.f, 0.f, 0.f};
  f32x4 acc[4][4];
#pragma unroll
  for (int i = 0; i < 4; ++i)
#pragma unroll
    for (int j = 0; j < 4; ++j) acc[i][j] = kZero;

  for (int kt = 0; kt < 8; ++kt) {
    const int kc = kt * 64;
    __syncthreads();
#pragma unroll
    for (int s2 = 0; s2 < 4; ++s2) {
      int bid = tid + 256 * s2;
      int row = bid >> 3, blk = bid & 7;
      half8 va = *(const half8*)&A[(size_t)(M0 + row) * 512 + kc + blk * 8];
      *(half8*)&At[row * 64 + ((blk ^ (row & 7)) * 8)] = va;
      half8 vb = *(const half8*)&Bm[(size_t)(N0 + row) * 512 + kc + blk * 8];
      *(half8*)&Bt[row * 64 + ((blk ^ (row & 7)) * 8)] = vb;
    }
    __syncthreads();
#pragma unroll
    for (int kk = 0; kk < 2; ++kk) {
      half8 af[4], bf[4];
#pragma unroll
      for (int i = 0; i < 4; ++i) {
        int ar = wm * 64 + i * 16 + li;
        af[i] = *(const half8*)&At[ar * 64 + (((4 * kk + g) ^ (ar & 7)) * 8)];
        int br = wn * 64 + i * 16 + li;
        bf[i] = *(const half8*)&Bt[br * 64 + (((4 * kk + g) ^ (br & 7)) * 8)];
      }
#pragma unroll
      for (int i = 0; i < 4; ++i)
#pragma unroll
        for (int j = 0; j < 4; ++j) acc[i][j] = MFMA16x32(af[i], bf[j], acc[i][j]);
    }
  }

  if (MODE == 2) {
#pragma unroll
    for (int i = 0; i < 4; ++i) {
      int trow = M0 + wm * 64 + i * 16 + 4 * g;
#pragma unroll
      for (int j = 0; j < 4; ++j) {
        int m = N0 + wn * 64 + j * 16 + li;
        float bs = bias[m];
#pragma unroll
        for (int r = 0; r < 4; ++r) {
          out[(size_t)(trow + r) * 512 + m] = (_Float16)(acc[i][j][r] + bs);
        }
      }
    }
  } else {
#pragma unroll
    for (int i = 0; i < 4; ++i) {
      int m0r = M0 + wm * 64 + i * 16 + 4 * g;
#pragma unroll
      for (int r = 0; r < 4; ++r) {
        int m = m0r + r;
        float bs = bias[m];
#pragma unroll
        for (int j = 0; j < 4; ++j) {
          int t = N0 + wn * 64 + j * 16 + li;
          out[(size_t)m * 16384 + t] = (_Float16)(acc[i][j][r] + bs);
        }
      }
    }
  }
}

// ---- S-GEMM: S[b][cc][d] = q[b,co+cc] . k[b,d], fp32 out --------------------
// grid (8, 16, 8): x = c-tile (128) within 1024-row chunk, y = d-tile, z = b.
__global__ __launch_bounds__(256) void s_gemm(
    const half_t* __restrict__ q, const half_t* __restrict__ k,
    float* __restrict__ S, int co) {
  __shared__ half_t At[128 * 64];
  __shared__ half_t Bt[128 * 64];
  const int tid = threadIdx.x;
  const int lane = tid & 63, wv = tid >> 6;
  const int g = lane >> 4, li = lane & 15;
  const int wm = wv >> 1, wn = wv & 1;
  const int b = blockIdx.z;
  const int M0 = blockIdx.x * 128;      // local c within chunk
  const int N0 = blockIdx.y * 128;      // d
  const half_t* Ab = q + (size_t)(b * 2048 + co + M0) * 512;
  const half_t* Bb = k + (size_t)(b * 2048 + N0) * 512;

  const f32x4 kZero = {0.f, 0.f, 0.f, 0.f};
  f32x4 acc[4][4];
#pragma unroll
  for (int i = 0; i < 4; ++i)
#pragma unroll
    for (int j = 0; j < 4; ++j) acc[i][j] = kZero;

  for (int kt = 0; kt < 8; ++kt) {
    const int kc = kt * 64;
    __syncthreads();
#pragma unroll
    for (int s2 = 0; s2 < 4; ++s2) {
      int bid = tid + 256 * s2;
      int row = bid >> 3, blk = bid & 7;
      half8 va = *(const half8*)&Ab[(size_t)row * 512 + kc + blk * 8];
      *(half8*)&At[row * 64 + ((blk ^ (row & 7)) * 8)] = va;
      half8 vb = *(const half8*)&Bb[(size_t)row * 512 + kc + blk * 8];
      *(half8*)&Bt[row * 64 + ((blk ^ (row & 7)) * 8)] = vb;
    }
    __syncthreads();
#pragma unroll
    for (int kk = 0; kk < 2; ++kk) {
      half8 af[4], bf[4];
#pragma unroll
      for (int i = 0; i < 4; ++i) {
        int ar = wm * 64 + i * 16 + li;
        af[i] = *(const half8*)&At[ar * 64 + (((4 * kk + g) ^ (ar & 7)) * 8)];
        int br = wn * 64 + i * 16 + li;
        bf[i] = *(const half8*)&Bt[br * 64 + (((4 * kk + g) ^ (br & 7)) * 8)];
      }
#pragma unroll
      for (int i = 0; i < 4; ++i)
#pragma unroll
        for (int j = 0; j < 4; ++j) acc[i][j] = MFMA16x32(af[i], bf[j], acc[i][j]);
    }
  }

  float* Sb = S + (size_t)(b * 1024 + M0) * 2048 + N0;
#pragma unroll
  for (int i = 0; i < 4; ++i) {
#pragma unroll
    for (int j = 0; j < 4; ++j) {
#pragma unroll
      for (int r = 0; r < 4; ++r) {
        Sb[(size_t)(wm * 64 + i * 16 + 4 * g + r) * 2048 + wn * 64 + j * 16 + li] =
            acc[i][j][r];
      }
    }
  }
}

// ---- row softmax: wave per row; P = exp(s - max) fp16 written IN-PLACE ------
// S rows 8192 x 2048 fp32; P[rr*4096 + d] overlays the row's own storage
// (full row read into registers before any write). lbuf[rr] = row sum.
__global__ __launch_bounds__(256) void softmax_rows(
    float* __restrict__ S, float* __restrict__ lbuf) {
  const int rr = blockIdx.x * 4 + (threadIdx.x >> 6);
  const int lane = threadIdx.x & 63;
  float* Srow = S + (size_t)rr * 2048;

  f32x4 v[8];
#pragma unroll
  for (int it = 0; it < 8; ++it) v[it] = *(const f32x4*)&Srow[lane * 4 + it * 256];

  float mx = -3e38f;
#pragma unroll
  for (int it = 0; it < 8; ++it)
    mx = fmaxf(mx, fmaxf(fmaxf(v[it][0], v[it][1]), fmaxf(v[it][2], v[it][3])));
  mx = fmaxf(mx, __shfl_xor(mx, 1));
  mx = fmaxf(mx, __shfl_xor(mx, 2));
  mx = fmaxf(mx, __shfl_xor(mx, 4));
  mx = fmaxf(mx, __shfl_xor(mx, 8));
  mx = fmaxf(mx, __shfl_xor(mx, 16));
  mx = fmaxf(mx, __shfl_xor(mx, 32));

  float sum = 0.f;
  half4 h[8];
#pragma unroll
  for (int it = 0; it < 8; ++it) {
#pragma unroll
    for (int j = 0; j < 4; ++j) {
      float p = __expf(v[it][j] - mx);
      sum += p;
      h[it][j] = (_Float16)p;
    }
  }
  sum += __shfl_xor(sum, 1);
  sum += __shfl_xor(sum, 2);
  sum += __shfl_xor(sum, 4);
  sum += __shfl_xor(sum, 8);
  sum += __shfl_xor(sum, 16);
  sum += __shfl_xor(sum, 32);

  half_t* P = (half_t*)S;
#pragma unroll
  for (int it = 0; it < 8; ++it)
    *(half4*)&P[(size_t)rr * 4096 + lane * 4 + it * 256] = h[it];
  if (lane == 0) lbuf[rr] = sum;
}

// ---- PV-GEMM: out[b][n][co+cc] = (P[b,cc] . V^T[n]) / (l * sqrt(512)) -------
// grid (8, 4, 8): x = c-tile (128) in chunk, y = n-tile (128), z = b.
// A = P (row stride 4096 halves, K=2048); B = vt[n][16384] at col b*2048.
__global__ __launch_bounds__(256) void pv_gemm(
    const half_t* __restrict__ P, const half_t* __restrict__ vt,
    const float* __restrict__ lbuf, float* __restrict__ outp, int co) {
  __shared__ half_t At[128 * 64];
  __shared__ half_t Bt[128 * 64];
  const int tid = threadIdx.x;
  const int lane = tid & 63, wv = tid >> 6;
  const int g = lane >> 4, li = lane & 15;
  const int wm = wv >> 1, wn = wv & 1;
  const int b = blockIdx.z;
  const int M0 = blockIdx.x * 128;      // local c within chunk
  const int N0 = blockIdx.y * 128;      // n
  const half_t* Ab = P + (size_t)(b * 1024 + M0) * 4096;
  const half_t* Bb = vt + (size_t)N0 * 16384 + (size_t)b * 2048;

  const f32x4 kZero = {0.f, 0.f, 0.f, 0.f};
  f32x4 acc[4][4];
#pragma unroll
  for (int i = 0; i < 4; ++i)
#pragma unroll
    for (int j = 0; j < 4; ++j) acc[i][j] = kZero;

#pragma unroll 1
  for (int kt = 0; kt < 32; ++kt) {
    const int kc = kt * 64;
    __syncthreads();
#pragma unroll
    for (int s2 = 0; s2 < 4; ++s2) {
      int bid = tid + 256 * s2;
      int row = bid >> 3, blk = bid & 7;
      half8 va = *(const half8*)&Ab[(size_t)row * 4096 + kc + blk * 8];
      *(half8*)&At[row * 64 + ((blk ^ (row & 7)) * 8)] = va;
      half8 vb = *(const half8*)&Bb[(size_t)row * 16384 + kc + blk * 8];
      *(half8*)&Bt[row * 64 + ((blk ^ (row & 7)) * 8)] = vb;
    }
    __syncthreads();
#pragma unroll
    for (int kk = 0; kk < 2; ++kk) {
      half8 af[4], bf[4];
#pragma unroll
      for (int i = 0; i < 4; ++i) {
        int ar = wm * 64 + i * 16 + li;
        af[i] = *(const half8*)&At[ar * 64 + (((4 * kk + g) ^ (ar & 7)) * 8)];
        int br = wn * 64 + i * 16 + li;
        bf[i] = *(const half8*)&Bt[br * 64 + (((4 * kk + g) ^ (br & 7)) * 8)];
      }
#pragma unroll
      for (int i = 0; i < 4; ++i)
#pragma unroll
        for (int j = 0; j < 4; ++j) acc[i][j] = MFMA16x32(af[i], bf[j], acc[i][j]);
    }
  }

  // epilogue: scale by 1/(l*sqrt(512)), transposed scatter out[b][n][c]
#pragma unroll
  for (int i = 0; i < 4; ++i) {
    int c0r = M0 + wm * 64 + i * 16 + 4 * g;   // + r (local c)
    float inv[4];
#pragma unroll
    for (int r = 0; r < 4; ++r)
      inv[r] = 1.0f / (lbuf[b * 1024 + c0r + r] * 22.62741699796952f);
#pragma unroll
    for (int j = 0; j < 4; ++j) {
      int n = N0 + wn * 64 + j * 16 + li;
      float* ob = outp + (size_t)b * 1048576 + (size_t)n * 2048 + co + c0r;
#pragma unroll
      for (int r = 0; r < 4; ++r) {
        ob[r] = acc[i][j][r] * inv[r];
      }
    }
  }
}

// ---------------------------------------------------------------------------
extern "C" void kernel_launch(void* const* d_in, const int* in_sizes, int n_in,
                              void* d_out, int out_size, void* d_ws, size_t ws_size,
                              hipStream_t stream) {
  const float* x  = (const float*)d_in[0];
  const float* Wq = (const float*)d_in[1];
  const float* bq = (const float*)d_in[2];
  const float* Wk = (const float*)d_in[3];
  const float* bk = (const float*)d_in[4];
  const float* Wv = (const float*)d_in[5];
  const float* bv = (const float*)d_in[6];

  // workspace layout (phases overlap in the S-region):
  half_t* qsb  = (half_t*)d_ws;                     // [16384][512]   16 MB
  half_t* ksb  = qsb + (size_t)16384 * 512;         // [16384][512]   16 MB
  half_t* vtb  = ksb + (size_t)16384 * 512;         // [512][16384]   16 MB
  half_t* xh   = vtb + (size_t)512 * 16384;         // [16384][512]   16 MB (proj phase)
  half_t* wqh  = xh  + (size_t)16384 * 512;         // [512][512]     0.5 MB
  half_t* wkh  = wqh + (size_t)512 * 512;
  half_t* wvh  = wkh + (size_t)512 * 512;
  float*  Sbuf = (float*)xh;                        // [8192][2048] fp32 67 MB (attn phase,
                                                    //  overlays xh+weights after projs)
  float*  lbuf = (float*)(((char*)d_ws) + (size_t)117 * 1024 * 1024);  // [8192] 32 KB

  cast_f16<<<dim3(16384 * 512 / 4 / 256), 256, 0, stream>>>(x, xh, 16384 * 512 / 4);
  cast_f16<<<dim3(512 * 512 / 4 / 256), 256, 0, stream>>>(Wq, wqh, 512 * 512 / 4);
  cast_f16<<<dim3(512 * 512 / 4 / 256), 256, 0, stream>>>(Wk, wkh, 512 * 512 / 4);
  cast_f16<<<dim3(512 * 512 / 4 / 256), 256, 0, stream>>>(Wv, wvh, 512 * 512 / 4);

  proj_gemm<2><<<dim3(128, 4), 256, 0, stream>>>(xh, wqh, bq, qsb);
  proj_gemm<2><<<dim3(128, 4), 256, 0, stream>>>(xh, wkh, bk, ksb);
  proj_gemm<1><<<dim3(4, 128), 256, 0, stream>>>(wvh, xh, bv, vtb);

  for (int chunk = 0; chunk < 2; ++chunk) {
    const int co = chunk * 1024;
    s_gemm<<<dim3(8, 16, 8), 256, 0, stream>>>(qsb, ksb, Sbuf, co);
    softmax_rows<<<dim3(2048), 256, 0, stream>>>(Sbuf, lbuf);
    pv_gemm<<<dim3(8, 4, 8), 256, 0, stream>>>((const half_t*)Sbuf, vtb, lbuf,
                                               (float*)d_out, co);
  }
}

// Round 16
// 228.419 us; speedup vs baseline: 1.8017x; 1.0677x over previous
//
#include <hip/hip_runtime.h>

// ---------------------------------------------------------------------------
// Fused QKV-projection + attention (B=8, C=2048, N=512), fp32 in/out.
// Round 16: GLOAD_LDS GEMM CORE. R15's materialized-S pipeline is legible:
// pv_gemm 2x44us top, all GEMMs on the old reg-staged LDS path (~500 TF
// class). Port the m97 step-3 structure (global_load_lds w/ pre-swizzled
// source == read-side XOR involution, double-buffered LDS, STAGE-then-compute,
// 1 barrier/K-step) into a unified gemm_core used by proj/s/pv. Everything
// else (softmax, casts, layouts, 2x1024-row chunks, epilogues) unchanged.
// Precision unchanged: absmax 3.36e-3 vs threshold 4.57e-3.
// ---------------------------------------------------------------------------

typedef _Float16 half_t;
typedef __attribute__((ext_vector_type(8))) _Float16 half8;
typedef __attribute__((ext_vector_type(4))) _Float16 half4;
typedef __attribute__((ext_vector_type(4))) float    f32x4;

#define MFMA16x32(A_, B_, C_) __builtin_amdgcn_mfma_f32_16x16x32_f16((A_), (B_), (C_), 0, 0, 0)

__device__ __forceinline__ void gload_lds16(const void* g, void* l) {
  __builtin_amdgcn_global_load_lds(
      (const __attribute__((address_space(1))) void*)g,
      (__attribute__((address_space(3))) void*)l, 16, 0, 0);
}

// ---- plain cast fp32 -> fp16 ------------------------------------------------
__global__ void cast_f16(const float* __restrict__ src, half_t* __restrict__ dst,
                         int total4) {
  int idx = blockIdx.x * 256 + threadIdx.x;
  if (idx >= total4) return;
  f32x4 v = ((const f32x4*)src)[idx];
  half4 h;
#pragma unroll
  for (int j = 0; j < 4; ++j) h[j] = (_Float16)v[j];
  *(half4*)&dst[(size_t)idx * 4] = h;
}

// ---- unified GEMM core: 128x128 tile, BK=64, double-buffered gload_lds ------
// LDS content identical to the old swizzled-write layout (XOR is an
// involution: linear dest + pre-swizzled source == swizzled dest + linear
// source), so the read side is unchanged. NKT = K/64; SA/SB = row strides
// (in halves) of A and B. acc[i][j] accumulates the 4x4 fragment grid.
template <int NKT, int SA, int SB>
__device__ __forceinline__ void gemm_core(
    const char* Abytes, const char* Bbytes,
    half_t (*At)[8192], half_t (*Bt)[8192], int tid, f32x4 acc[4][4]) {
  const int lane = tid & 63;
  const int wv = tid >> 6;
  const int g = lane >> 4, li = lane & 15;
  const int wm = wv >> 1, wn = wv & 1;

  auto STAGE = [&](int kc, int buf) {
#pragma unroll
    for (int i2 = 0; i2 < 4; ++i2) {
      int seg = i2 * 256 + tid;
      int row = seg >> 3, blk = seg & 7;
      int bsrc = blk ^ (row & 7);
      gload_lds16(Abytes + ((size_t)row * SA + kc + bsrc * 8) * 2,
                  (void*)&At[buf][seg * 8]);
    }
#pragma unroll
    for (int i2 = 0; i2 < 4; ++i2) {
      int seg = i2 * 256 + tid;
      int row = seg >> 3, blk = seg & 7;
      int bsrc = blk ^ (row & 7);
      gload_lds16(Bbytes + ((size_t)row * SB + kc + bsrc * 8) * 2,
                  (void*)&Bt[buf][seg * 8]);
    }
  };

  STAGE(0, 0);
  __syncthreads();
  int cur = 0;
#pragma unroll 1
  for (int kt = 0; kt < NKT; ++kt) {
    if (kt + 1 < NKT) STAGE((kt + 1) * 64, cur ^ 1);   // prefetch next K-step
#pragma unroll
    for (int kk = 0; kk < 2; ++kk) {
      half8 af[4], bf[4];
#pragma unroll
      for (int i = 0; i < 4; ++i) {
        int ar = wm * 64 + i * 16 + li;
        af[i] = *(const half8*)&At[cur][ar * 64 + (((4 * kk + g) ^ (ar & 7)) * 8)];
        int br = wn * 64 + i * 16 + li;
        bf[i] = *(const half8*)&Bt[cur][br * 64 + (((4 * kk + g) ^ (br & 7)) * 8)];
      }
#pragma unroll
      for (int i = 0; i < 4; ++i)
#pragma unroll
        for (int j = 0; j < 4; ++j) acc[i][j] = MFMA16x32(af[i], bf[j], acc[i][j]);
    }
    __syncthreads();   // drains vmcnt -> prefetched buffer ready for all waves
    cur ^= 1;
  }
}

// ---- projection GEMM: C[M][512] = A[M][512] . B[512][512]^T + bias ----------
// MODE 2: out[t*512 + m] = f16(val)     (q/k compact; A=x tokens, B=W)
// MODE 1: out[m*16384 + t] = f16(val)   (v transposed;  A=Wv,     B=x)
template <int MODE>
__global__ __launch_bounds__(256) void proj_gemm(
    const half_t* __restrict__ A, const half_t* __restrict__ Bm,
    const float* __restrict__ bias, half_t* __restrict__ out) {
  __shared__ half_t At[2][8192];
  __shared__ half_t Bt[2][8192];
  const int tid = threadIdx.x;
  const int lane = tid & 63, wv = tid >> 6;
  const int g = lane >> 4, li = lane & 15;
  const int wm = wv >> 1, wn = wv & 1;
  const int M0 = blockIdx.x * 128, N0 = blockIdx.y * 128;

  const f32x4 kZero = {0.f, 0.f, 0.f, 0.f};
  f32x4 acc[4][4];
#pragma unroll
  for (int i = 0; i < 4; ++i)
#pragma unroll
    for (int j = 0; j < 4; ++j) acc[i][j] = kZero;

  gemm_core<8, 512, 512>((const char*)(A + (size_t)M0 * 512),
                         (const char*)(Bm + (size_t)N0 * 512), At, Bt, tid, acc);

  if (MODE == 2) {
#pragma unroll
    for (int i = 0; i < 4; ++i) {
      int trow = M0 + wm * 64 + i * 16 + 4 * g;
#pragma unroll
      for (int j = 0; j < 4; ++j) {
        int m = N0 + wn * 64 + j * 16 + li;
        float bs = bias[m];
#pragma unroll
        for (int r = 0; r < 4; ++r) {
          out[(size_t)(trow + r) * 512 + m] = (_Float16)(acc[i][j][r] + bs);
        }
      }
    }
  } else {
#pragma unroll
    for (int i = 0; i < 4; ++i) {
      int m0r = M0 + wm * 64 + i * 16 + 4 * g;
#pragma unroll
      for (int r = 0; r < 4; ++r) {
        int m = m0r + r;
        float bs = bias[m];
#pragma unroll
        for (int j = 0; j < 4; ++j) {
          int t = N0 + wn * 64 + j * 16 + li;
          out[(size_t)m * 16384 + t] = (_Float16)(acc[i][j][r] + bs);
        }
      }
    }
  }
}

// ---- S-GEMM: S[b][cc][d] = q[b,co+cc] . k[b,d], fp32 out --------------------
// grid (8, 16, 8): x = c-tile (128) within 1024-row chunk, y = d-tile, z = b.
__global__ __launch_bounds__(256) void s_gemm(
    const half_t* __restrict__ q, const half_t* __restrict__ k,
    float* __restrict__ S, int co) {
  __shared__ half_t At[2][8192];
  __shared__ half_t Bt[2][8192];
  const int tid = threadIdx.x;
  const int lane = tid & 63, wv = tid >> 6;
  const int g = lane >> 4, li = lane & 15;
  const int wm = wv >> 1, wn = wv & 1;
  const int b = blockIdx.z;
  const int M0 = blockIdx.x * 128;      // local c within chunk
  const int N0 = blockIdx.y * 128;      // d

  const f32x4 kZero = {0.f, 0.f, 0.f, 0.f};
  f32x4 acc[4][4];
#pragma unroll
  for (int i = 0; i < 4; ++i)
#pragma unroll
    for (int j = 0; j < 4; ++j) acc[i][j] = kZero;

  gemm_core<8, 512, 512>(
      (const char*)(q + (size_t)(b * 2048 + co + M0) * 512),
      (const char*)(k + (size_t)(b * 2048 + N0) * 512), At, Bt, tid, acc);

  float* Sb = S + (size_t)(b * 1024 + M0) * 2048 + N0;
#pragma unroll
  for (int i = 0; i < 4; ++i) {
#pragma unroll
    for (int j = 0; j < 4; ++j) {
#pragma unroll
      for (int r = 0; r < 4; ++r) {
        Sb[(size_t)(wm * 64 + i * 16 + 4 * g + r) * 2048 + wn * 64 + j * 16 + li] =
            acc[i][j][r];
      }
    }
  }
}

// ---- row softmax: wave per row; P = exp(s - max) fp16 written IN-PLACE ------
// S rows 8192 x 2048 fp32; P[rr*4096 + d] overlays the row's own storage
// (full row read into registers before any write). lbuf[rr] = row sum.
__global__ __launch_bounds__(256) void softmax_rows(
    float* __restrict__ S, float* __restrict__ lbuf) {
  const int rr = blockIdx.x * 4 + (threadIdx.x >> 6);
  const int lane = threadIdx.x & 63;
  float* Srow = S + (size_t)rr * 2048;

  f32x4 v[8];
#pragma unroll
  for (int it = 0; it < 8; ++it) v[it] = *(const f32x4*)&Srow[lane * 4 + it * 256];

  float mx = -3e38f;
#pragma unroll
  for (int it = 0; it < 8; ++it)
    mx = fmaxf(mx, fmaxf(fmaxf(v[it][0], v[it][1]), fmaxf(v[it][2], v[it][3])));
  mx = fmaxf(mx, __shfl_xor(mx, 1));
  mx = fmaxf(mx, __shfl_xor(mx, 2));
  mx = fmaxf(mx, __shfl_xor(mx, 4));
  mx = fmaxf(mx, __shfl_xor(mx, 8));
  mx = fmaxf(mx, __shfl_xor(mx, 16));
  mx = fmaxf(mx, __shfl_xor(mx, 32));

  float sum = 0.f;
  half4 h[8];
#pragma unroll
  for (int it = 0; it < 8; ++it) {
#pragma unroll
    for (int j = 0; j < 4; ++j) {
      float p = __expf(v[it][j] - mx);
      sum += p;
      h[it][j] = (_Float16)p;
    }
  }
  sum += __shfl_xor(sum, 1);
  sum += __shfl_xor(sum, 2);
  sum += __shfl_xor(sum, 4);
  sum += __shfl_xor(sum, 8);
  sum += __shfl_xor(sum, 16);
  sum += __shfl_xor(sum, 32);

  half_t* P = (half_t*)S;
#pragma unroll
  for (int it = 0; it < 8; ++it)
    *(half4*)&P[(size_t)rr * 4096 + lane * 4 + it * 256] = h[it];
  if (lane == 0) lbuf[rr] = sum;
}

// ---- PV-GEMM: out[b][n][co+cc] = (P[b,cc] . V^T[n]) / (l * sqrt(512)) -------
// grid (8, 4, 8): x = c-tile (128) in chunk, y = n-tile (128), z = b.
// A = P (row stride 4096 halves, K=2048); B = vt[n][16384] at col b*2048.
__global__ __launch_bounds__(256) void pv_gemm(
    const half_t* __restrict__ P, const half_t* __restrict__ vt,
    const float* __restrict__ lbuf, float* __restrict__ outp, int co) {
  __shared__ half_t At[2][8192];
  __shared__ half_t Bt[2][8192];
  const int tid = threadIdx.x;
  const int lane = tid & 63, wv = tid >> 6;
  const int g = lane >> 4, li = lane & 15;
  const int wm = wv >> 1, wn = wv & 1;
  const int b = blockIdx.z;
  const int M0 = blockIdx.x * 128;      // local c within chunk
  const int N0 = blockIdx.y * 128;      // n

  const f32x4 kZero = {0.f, 0.f, 0.f, 0.f};
  f32x4 acc[4][4];
#pragma unroll
  for (int i = 0; i < 4; ++i)
#pragma unroll
    for (int j = 0; j < 4; ++j) acc[i][j] = kZero;

  gemm_core<32, 4096, 16384>(
      (const char*)(P + (size_t)(b * 1024 + M0) * 4096),
      (const char*)(vt + (size_t)N0 * 16384 + (size_t)b * 2048), At, Bt, tid, acc);

  // epilogue: scale by 1/(l*sqrt(512)), transposed scatter out[b][n][c]
#pragma unroll
  for (int i = 0; i < 4; ++i) {
    int c0r = M0 + wm * 64 + i * 16 + 4 * g;   // + r (local c)
    float inv[4];
#pragma unroll
    for (int r = 0; r < 4; ++r)
      inv[r] = 1.0f / (lbuf[b * 1024 + c0r + r] * 22.62741699796952f);
#pragma unroll
    for (int j = 0; j < 4; ++j) {
      int n = N0 + wn * 64 + j * 16 + li;
      float* ob = outp + (size_t)b * 1048576 + (size_t)n * 2048 + co + c0r;
#pragma unroll
      for (int r = 0; r < 4; ++r) {
        ob[r] = acc[i][j][r] * inv[r];
      }
    }
  }
}

// ---------------------------------------------------------------------------
extern "C" void kernel_launch(void* const* d_in, const int* in_sizes, int n_in,
                              void* d_out, int out_size, void* d_ws, size_t ws_size,
                              hipStream_t stream) {
  const float* x  = (const float*)d_in[0];
  const float* Wq = (const float*)d_in[1];
  const float* bq = (const float*)d_in[2];
  const float* Wk = (const float*)d_in[3];
  const float* bk = (const float*)d_in[4];
  const float* Wv = (const float*)d_in[5];
  const float* bv = (const float*)d_in[6];

  // workspace layout (phases overlap in the S-region):
  half_t* qsb  = (half_t*)d_ws;                     // [16384][512]   16 MB
  half_t* ksb  = qsb + (size_t)16384 * 512;         // [16384][512]   16 MB
  half_t* vtb  = ksb + (size_t)16384 * 512;         // [512][16384]   16 MB
  half_t* xh   = vtb + (size_t)512 * 16384;         // [16384][512]   16 MB (proj phase)
  half_t* wqh  = xh  + (size_t)16384 * 512;         // [512][512]     0.5 MB
  half_t* wkh  = wqh + (size_t)512 * 512;
  half_t* wvh  = wkh + (size_t)512 * 512;
  float*  Sbuf = (float*)xh;                        // [8192][2048] fp32 67 MB (attn phase,
                                                    //  overlays xh+weights after projs)
  float*  lbuf = (float*)(((char*)d_ws) + (size_t)117 * 1024 * 1024);  // [8192] 32 KB

  cast_f16<<<dim3(16384 * 512 / 4 / 256), 256, 0, stream>>>(x, xh, 16384 * 512 / 4);
  cast_f16<<<dim3(512 * 512 / 4 / 256), 256, 0, stream>>>(Wq, wqh, 512 * 512 / 4);
  cast_f16<<<dim3(512 * 512 / 4 / 256), 256, 0, stream>>>(Wk, wkh, 512 * 512 / 4);
  cast_f16<<<dim3(512 * 512 / 4 / 256), 256, 0, stream>>>(Wv, wvh, 512 * 512 / 4);

  proj_gemm<2><<<dim3(128, 4), 256, 0, stream>>>(xh, wqh, bq, qsb);
  proj_gemm<2><<<dim3(128, 4), 256, 0, stream>>>(xh, wkh, bk, ksb);
  proj_gemm<1><<<dim3(4, 128), 256, 0, stream>>>(wvh, xh, bv, vtb);

  for (int chunk = 0; chunk < 2; ++chunk) {
    const int co = chunk * 1024;
    s_gemm<<<dim3(8, 16, 8), 256, 0, stream>>>(qsb, ksb, Sbuf, co);
    softmax_rows<<<dim3(2048), 256, 0, stream>>>(Sbuf, lbuf);
    pv_gemm<<<dim3(8, 4, 8), 256, 0, stream>>>((const half_t*)Sbuf, vtb, lbuf,
                                               (float*)d_out, co);
  }
}

// Round 17
// 221.655 us; speedup vs baseline: 1.8566x; 1.0305x over previous
//
#include <hip/hip_runtime.h>

// ---------------------------------------------------------------------------
// Fused QKV-projection + attention (B=8, C=2048, N=512), fp32 in/out.
// Round 17: BATCH->XCD AFFINITY (T1). R16's pv_gemm fetched 84 MB vs 50 MB
// unique (P+V): grid (8c,4n,8b) sprays each batch's blocks over all 8 XCDs,
// thrashing the per-XCD 4 MB L2. Now s_gemm/pv_gemm use linear grids with
// b = blockIdx.x & 7: all 32 pv blocks of a batch (= 32 CUs = one XCD) are
// co-resident on one XCD; P(4MB)+V(4MB) panels get L2 reuse (4x for P rows,
// 8x for V rows). s_gemm same decode (q 1MB + k 2MB fully L2-resident).
// Everything else byte-identical to R16. absmax unchanged 3.36e-3.
// ---------------------------------------------------------------------------

typedef _Float16 half_t;
typedef __attribute__((ext_vector_type(8))) _Float16 half8;
typedef __attribute__((ext_vector_type(4))) _Float16 half4;
typedef __attribute__((ext_vector_type(4))) float    f32x4;

#define MFMA16x32(A_, B_, C_) __builtin_amdgcn_mfma_f32_16x16x32_f16((A_), (B_), (C_), 0, 0, 0)

__device__ __forceinline__ void gload_lds16(const void* g, void* l) {
  __builtin_amdgcn_global_load_lds(
      (const __attribute__((address_space(1))) void*)g,
      (__attribute__((address_space(3))) void*)l, 16, 0, 0);
}

// ---- plain cast fp32 -> fp16 ------------------------------------------------
__global__ void cast_f16(const float* __restrict__ src, half_t* __restrict__ dst,
                         int total4) {
  int idx = blockIdx.x * 256 + threadIdx.x;
  if (idx >= total4) return;
  f32x4 v = ((const f32x4*)src)[idx];
  half4 h;
#pragma unroll
  for (int j = 0; j < 4; ++j) h[j] = (_Float16)v[j];
  *(half4*)&dst[(size_t)idx * 4] = h;
}

// ---- unified GEMM core: 128x128 tile, BK=64, double-buffered gload_lds ------
// Linear LDS dest + pre-swizzled source (XOR involution) == swizzled layout.
// NKT = K/64; SA/SB = row strides (halves). acc = 4x4 fragment grid.
template <int NKT, int SA, int SB>
__device__ __forceinline__ void gemm_core(
    const char* Abytes, const char* Bbytes,
    half_t (*At)[8192], half_t (*Bt)[8192], int tid, f32x4 acc[4][4]) {
  const int lane = tid & 63;
  const int wv = tid >> 6;
  const int g = lane >> 4, li = lane & 15;
  const int wm = wv >> 1, wn = wv & 1;

  auto STAGE = [&](int kc, int buf) {
#pragma unroll
    for (int i2 = 0; i2 < 4; ++i2) {
      int seg = i2 * 256 + tid;
      int row = seg >> 3, blk = seg & 7;
      int bsrc = blk ^ (row & 7);
      gload_lds16(Abytes + ((size_t)row * SA + kc + bsrc * 8) * 2,
                  (void*)&At[buf][seg * 8]);
    }
#pragma unroll
    for (int i2 = 0; i2 < 4; ++i2) {
      int seg = i2 * 256 + tid;
      int row = seg >> 3, blk = seg & 7;
      int bsrc = blk ^ (row & 7);
      gload_lds16(Bbytes + ((size_t)row * SB + kc + bsrc * 8) * 2,
                  (void*)&Bt[buf][seg * 8]);
    }
  };

  STAGE(0, 0);
  __syncthreads();
  int cur = 0;
#pragma unroll 1
  for (int kt = 0; kt < NKT; ++kt) {
    if (kt + 1 < NKT) STAGE((kt + 1) * 64, cur ^ 1);   // prefetch next K-step
#pragma unroll
    for (int kk = 0; kk < 2; ++kk) {
      half8 af[4], bf[4];
#pragma unroll
      for (int i = 0; i < 4; ++i) {
        int ar = wm * 64 + i * 16 + li;
        af[i] = *(const half8*)&At[cur][ar * 64 + (((4 * kk + g) ^ (ar & 7)) * 8)];
        int br = wn * 64 + i * 16 + li;
        bf[i] = *(const half8*)&Bt[cur][br * 64 + (((4 * kk + g) ^ (br & 7)) * 8)];
      }
#pragma unroll
      for (int i = 0; i < 4; ++i)
#pragma unroll
        for (int j = 0; j < 4; ++j) acc[i][j] = MFMA16x32(af[i], bf[j], acc[i][j]);
    }
    __syncthreads();   // drains vmcnt -> prefetched buffer ready for all waves
    cur ^= 1;
  }
}

// ---- projection GEMM: C[M][512] = A[M][512] . B[512][512]^T + bias ----------
// MODE 2: out[t*512 + m] = f16(val)     (q/k compact; A=x tokens, B=W)
// MODE 1: out[m*16384 + t] = f16(val)   (v transposed;  A=Wv,     B=x)
template <int MODE>
__global__ __launch_bounds__(256) void proj_gemm(
    const half_t* __restrict__ A, const half_t* __restrict__ Bm,
    const float* __restrict__ bias, half_t* __restrict__ out) {
  __shared__ half_t At[2][8192];
  __shared__ half_t Bt[2][8192];
  const int tid = threadIdx.x;
  const int lane = tid & 63, wv = tid >> 6;
  const int g = lane >> 4, li = lane & 15;
  const int wm = wv >> 1, wn = wv & 1;
  const int M0 = blockIdx.x * 128, N0 = blockIdx.y * 128;

  const f32x4 kZero = {0.f, 0.f, 0.f, 0.f};
  f32x4 acc[4][4];
#pragma unroll
  for (int i = 0; i < 4; ++i)
#pragma unroll
    for (int j = 0; j < 4; ++j) acc[i][j] = kZero;

  gemm_core<8, 512, 512>((const char*)(A + (size_t)M0 * 512),
                         (const char*)(Bm + (size_t)N0 * 512), At, Bt, tid, acc);

  if (MODE == 2) {
#pragma unroll
    for (int i = 0; i < 4; ++i) {
      int trow = M0 + wm * 64 + i * 16 + 4 * g;
#pragma unroll
      for (int j = 0; j < 4; ++j) {
        int m = N0 + wn * 64 + j * 16 + li;
        float bs = bias[m];
#pragma unroll
        for (int r = 0; r < 4; ++r) {
          out[(size_t)(trow + r) * 512 + m] = (_Float16)(acc[i][j][r] + bs);
        }
      }
    }
  } else {
#pragma unroll
    for (int i = 0; i < 4; ++i) {
      int m0r = M0 + wm * 64 + i * 16 + 4 * g;
#pragma unroll
      for (int r = 0; r < 4; ++r) {
        int m = m0r + r;
        float bs = bias[m];
#pragma unroll
        for (int j = 0; j < 4; ++j) {
          int t = N0 + wn * 64 + j * 16 + li;
          out[(size_t)m * 16384 + t] = (_Float16)(acc[i][j][r] + bs);
        }
      }
    }
  }
}

// ---- S-GEMM: S[b][cc][d] = q[b,co+cc] . k[b,d], fp32 out --------------------
// grid 1024 linear, batch->XCD affine: b = id & 7 (hw round-robin id%8 = XCD),
// idx = id >> 3: M0 = (idx & 7)*128 (c-tile), N0 = (idx >> 3)*128 (d-tile).
__global__ __launch_bounds__(256) void s_gemm(
    const half_t* __restrict__ q, const half_t* __restrict__ k,
    float* __restrict__ S, int co) {
  __shared__ half_t At[2][8192];
  __shared__ half_t Bt[2][8192];
  const int tid = threadIdx.x;
  const int lane = tid & 63, wv = tid >> 6;
  const int g = lane >> 4, li = lane & 15;
  const int wm = wv >> 1, wn = wv & 1;
  const int id = blockIdx.x;
  const int b = id & 7;
  const int idx = id >> 3;
  const int M0 = (idx & 7) * 128;       // local c within chunk
  const int N0 = (idx >> 3) * 128;      // d

  const f32x4 kZero = {0.f, 0.f, 0.f, 0.f};
  f32x4 acc[4][4];
#pragma unroll
  for (int i = 0; i < 4; ++i)
#pragma unroll
    for (int j = 0; j < 4; ++j) acc[i][j] = kZero;

  gemm_core<8, 512, 512>(
      (const char*)(q + (size_t)(b * 2048 + co + M0) * 512),
      (const char*)(k + (size_t)(b * 2048 + N0) * 512), At, Bt, tid, acc);

  float* Sb = S + (size_t)(b * 1024 + M0) * 2048 + N0;
#pragma unroll
  for (int i = 0; i < 4; ++i) {
#pragma unroll
    for (int j = 0; j < 4; ++j) {
#pragma unroll
      for (int r = 0; r < 4; ++r) {
        Sb[(size_t)(wm * 64 + i * 16 + 4 * g + r) * 2048 + wn * 64 + j * 16 + li] =
            acc[i][j][r];
      }
    }
  }
}

// ---- row softmax: wave per row; P = exp(s - max) fp16 written IN-PLACE ------
__global__ __launch_bounds__(256) void softmax_rows(
    float* __restrict__ S, float* __restrict__ lbuf) {
  const int rr = blockIdx.x * 4 + (threadIdx.x >> 6);
  const int lane = threadIdx.x & 63;
  float* Srow = S + (size_t)rr * 2048;

  f32x4 v[8];
#pragma unroll
  for (int it = 0; it < 8; ++it) v[it] = *(const f32x4*)&Srow[lane * 4 + it * 256];

  float mx = -3e38f;
#pragma unroll
  for (int it = 0; it < 8; ++it)
    mx = fmaxf(mx, fmaxf(fmaxf(v[it][0], v[it][1]), fmaxf(v[it][2], v[it][3])));
  mx = fmaxf(mx, __shfl_xor(mx, 1));
  mx = fmaxf(mx, __shfl_xor(mx, 2));
  mx = fmaxf(mx, __shfl_xor(mx, 4));
  mx = fmaxf(mx, __shfl_xor(mx, 8));
  mx = fmaxf(mx, __shfl_xor(mx, 16));
  mx = fmaxf(mx, __shfl_xor(mx, 32));

  float sum = 0.f;
  half4 h[8];
#pragma unroll
  for (int it = 0; it < 8; ++it) {
#pragma unroll
    for (int j = 0; j < 4; ++j) {
      float p = __expf(v[it][j] - mx);
      sum += p;
      h[it][j] = (_Float16)p;
    }
  }
  sum += __shfl_xor(sum, 1);
  sum += __shfl_xor(sum, 2);
  sum += __shfl_xor(sum, 4);
  sum += __shfl_xor(sum, 8);
  sum += __shfl_xor(sum, 16);
  sum += __shfl_xor(sum, 32);

  half_t* P = (half_t*)S;
#pragma unroll
  for (int it = 0; it < 8; ++it)
    *(half4*)&P[(size_t)rr * 4096 + lane * 4 + it * 256] = h[it];
  if (lane == 0) lbuf[rr] = sum;
}

// ---- PV-GEMM: out[b][n][co+cc] = (P[b,cc] . V^T[n]) / (l * sqrt(512)) -------
// grid 256 linear, batch->XCD affine: b = id & 7 -> one batch per XCD
// (32 blocks = 32 CUs, all co-resident; P/V panels L2-reused).
__global__ __launch_bounds__(256) void pv_gemm(
    const half_t* __restrict__ P, const half_t* __restrict__ vt,
    const float* __restrict__ lbuf, float* __restrict__ outp, int co) {
  __shared__ half_t At[2][8192];
  __shared__ half_t Bt[2][8192];
  const int tid = threadIdx.x;
  const int lane = tid & 63, wv = tid >> 6;
  const int g = lane >> 4, li = lane & 15;
  const int wm = wv >> 1, wn = wv & 1;
  const int id = blockIdx.x;
  const int b = id & 7;
  const int idx = id >> 3;
  const int M0 = (idx >> 2) * 128;      // local c within chunk
  const int N0 = (idx & 3) * 128;       // n

  const f32x4 kZero = {0.f, 0.f, 0.f, 0.f};
  f32x4 acc[4][4];
#pragma unroll
  for (int i = 0; i < 4; ++i)
#pragma unroll
    for (int j = 0; j < 4; ++j) acc[i][j] = kZero;

  gemm_core<32, 4096, 16384>(
      (const char*)(P + (size_t)(b * 1024 + M0) * 4096),
      (const char*)(vt + (size_t)N0 * 16384 + (size_t)b * 2048), At, Bt, tid, acc);

  // epilogue: scale by 1/(l*sqrt(512)), transposed scatter out[b][n][c]
#pragma unroll
  for (int i = 0; i < 4; ++i) {
    int c0r = M0 + wm * 64 + i * 16 + 4 * g;   // + r (local c)
    float inv[4];
#pragma unroll
    for (int r = 0; r < 4; ++r)
      inv[r] = 1.0f / (lbuf[b * 1024 + c0r + r] * 22.62741699796952f);
#pragma unroll
    for (int j = 0; j < 4; ++j) {
      int n = N0 + wn * 64 + j * 16 + li;
      float* ob = outp + (size_t)b * 1048576 + (size_t)n * 2048 + co + c0r;
#pragma unroll
      for (int r = 0; r < 4; ++r) {
        ob[r] = acc[i][j][r] * inv[r];
      }
    }
  }
}

// ---------------------------------------------------------------------------
extern "C" void kernel_launch(void* const* d_in, const int* in_sizes, int n_in,
                              void* d_out, int out_size, void* d_ws, size_t ws_size,
                              hipStream_t stream) {
  const float* x  = (const float*)d_in[0];
  const float* Wq = (const float*)d_in[1];
  const float* bq = (const float*)d_in[2];
  const float* Wk = (const float*)d_in[3];
  const float* bk = (const float*)d_in[4];
  const float* Wv = (const float*)d_in[5];
  const float* bv = (const float*)d_in[6];

  // workspace layout (phases overlap in the S-region):
  half_t* qsb  = (half_t*)d_ws;                     // [16384][512]   16 MB
  half_t* ksb  = qsb + (size_t)16384 * 512;         // [16384][512]   16 MB
  half_t* vtb  = ksb + (size_t)16384 * 512;         // [512][16384]   16 MB
  half_t* xh   = vtb + (size_t)512 * 16384;         // [16384][512]   16 MB (proj phase)
  half_t* wqh  = xh  + (size_t)16384 * 512;         // [512][512]     0.5 MB
  half_t* wkh  = wqh + (size_t)512 * 512;
  half_t* wvh  = wkh + (size_t)512 * 512;
  float*  Sbuf = (float*)xh;                        // [8192][2048] fp32 67 MB (attn phase)
  float*  lbuf = (float*)(((char*)d_ws) + (size_t)117 * 1024 * 1024);  // [8192]

  cast_f16<<<dim3(16384 * 512 / 4 / 256), 256, 0, stream>>>(x, xh, 16384 * 512 / 4);
  cast_f16<<<dim3(512 * 512 / 4 / 256), 256, 0, stream>>>(Wq, wqh, 512 * 512 / 4);
  cast_f16<<<dim3(512 * 512 / 4 / 256), 256, 0, stream>>>(Wk, wkh, 512 * 512 / 4);
  cast_f16<<<dim3(512 * 512 / 4 / 256), 256, 0, stream>>>(Wv, wvh, 512 * 512 / 4);

  proj_gemm<2><<<dim3(128, 4), 256, 0, stream>>>(xh, wqh, bq, qsb);
  proj_gemm<2><<<dim3(128, 4), 256, 0, stream>>>(xh, wkh, bk, ksb);
  proj_gemm<1><<<dim3(4, 128), 256, 0, stream>>>(wvh, xh, bv, vtb);

  for (int chunk = 0; chunk < 2; ++chunk) {
    const int co = chunk * 1024;
    s_gemm<<<dim3(1024), 256, 0, stream>>>(qsb, ksb, Sbuf, co);
    softmax_rows<<<dim3(2048), 256, 0, stream>>>(Sbuf, lbuf);
    pv_gemm<<<dim3(256), 256, 0, stream>>>((const half_t*)Sbuf, vtb, lbuf,
                                           (float*)d_out, co);
  }
}

// Round 18
// 206.027 us; speedup vs baseline: 1.9975x; 1.0759x over previous
//
#include <hip/hip_runtime.h>

// ---------------------------------------------------------------------------
// Fused QKV-projection + attention (B=8, C=2048, N=512), fp32 in/out.
// Round 18: M64 TILES FOR s/pv (occupancy for the 2-phase core). The 2-phase
// gemm_core hides its stage+barrier critical path via cross-block wave overlap
// (m114/m233); pv's grid 256 = 1 block/CU had NO overlap partner. M-tile
// 128->64 for s_gemm/pv_gemm: LDS 64->48 KB (3 blocks/CU resident), grids
// 2048/512 (>=2 blocks/CU co-resident), batch->XCD affinity kept (grids ≡ 0
// mod 8). Per-output K-order unchanged -> BIT-IDENTICAL output (absmax must
// stay 3.356934e-3). Projections keep M=128. Everything else = R17.
// ---------------------------------------------------------------------------

typedef _Float16 half_t;
typedef __attribute__((ext_vector_type(8))) _Float16 half8;
typedef __attribute__((ext_vector_type(4))) _Float16 half4;
typedef __attribute__((ext_vector_type(4))) float    f32x4;

#define MFMA16x32(A_, B_, C_) __builtin_amdgcn_mfma_f32_16x16x32_f16((A_), (B_), (C_), 0, 0, 0)

__device__ __forceinline__ void gload_lds16(const void* g, void* l) {
  __builtin_amdgcn_global_load_lds(
      (const __attribute__((address_space(1))) void*)g,
      (__attribute__((address_space(3))) void*)l, 16, 0, 0);
}

// ---- plain cast fp32 -> fp16 ------------------------------------------------
__global__ void cast_f16(const float* __restrict__ src, half_t* __restrict__ dst,
                         int total4) {
  int idx = blockIdx.x * 256 + threadIdx.x;
  if (idx >= total4) return;
  f32x4 v = ((const f32x4*)src)[idx];
  half4 h;
#pragma unroll
  for (int j = 0; j < 4; ++j) h[j] = (_Float16)v[j];
  *(half4*)&dst[(size_t)idx * 4] = h;
}

// ---- unified GEMM core: (MR*32)x128 tile, BK=64, dbuf gload_lds -------------
// Linear LDS dest + pre-swizzled source (XOR involution) == swizzled layout.
// NKT = K/64; SA/SB = row strides (halves); MR = M/32 (4 -> 128 rows, 2 -> 64).
// At buffer = 2 x MR*2048 halves; Bt = 2 x 8192 halves.
template <int NKT, int SA, int SB, int MR>
__device__ __forceinline__ void gemm_core(
    const char* Abytes, const char* Bbytes,
    half_t* At, half_t* Bt, int tid, f32x4 (&acc)[MR][4]) {
  const int lane = tid & 63;
  const int wv = tid >> 6;
  const int g = lane >> 4, li = lane & 15;
  const int wm = wv >> 1, wn = wv & 1;
  const int ASTRIDE = MR * 2048;

  auto STAGE = [&](int kc, int buf) {
#pragma unroll
    for (int i2 = 0; i2 < MR; ++i2) {
      int seg = i2 * 256 + tid;
      int row = seg >> 3, blk = seg & 7;
      int bsrc = blk ^ (row & 7);
      gload_lds16(Abytes + ((size_t)row * SA + kc + bsrc * 8) * 2,
                  (void*)&At[buf * ASTRIDE + seg * 8]);
    }
#pragma unroll
    for (int i2 = 0; i2 < 4; ++i2) {
      int seg = i2 * 256 + tid;
      int row = seg >> 3, blk = seg & 7;
      int bsrc = blk ^ (row & 7);
      gload_lds16(Bbytes + ((size_t)row * SB + kc + bsrc * 8) * 2,
                  (void*)&Bt[buf * 8192 + seg * 8]);
    }
  };

  STAGE(0, 0);
  __syncthreads();
  int cur = 0;
#pragma unroll 1
  for (int kt = 0; kt < NKT; ++kt) {
    if (kt + 1 < NKT) STAGE((kt + 1) * 64, cur ^ 1);   // prefetch next K-step
#pragma unroll
    for (int kk = 0; kk < 2; ++kk) {
      half8 af[MR], bf[4];
#pragma unroll
      for (int i = 0; i < MR; ++i) {
        int ar = wm * (MR * 16) + i * 16 + li;
        af[i] = *(const half8*)&At[cur * ASTRIDE + ar * 64 + (((4 * kk + g) ^ (ar & 7)) * 8)];
      }
#pragma unroll
      for (int j = 0; j < 4; ++j) {
        int br = wn * 64 + j * 16 + li;
        bf[j] = *(const half8*)&Bt[cur * 8192 + br * 64 + (((4 * kk + g) ^ (br & 7)) * 8)];
      }
#pragma unroll
      for (int i = 0; i < MR; ++i)
#pragma unroll
        for (int j = 0; j < 4; ++j) acc[i][j] = MFMA16x32(af[i], bf[j], acc[i][j]);
    }
    __syncthreads();   // drains vmcnt -> prefetched buffer ready for all waves
    cur ^= 1;
  }
}

// ---- projection GEMM: C[M][512] = A[M][512] . B[512][512]^T + bias ----------
// MODE 2: out[t*512 + m] = f16(val)     (q/k compact; A=x tokens, B=W)
// MODE 1: out[m*16384 + t] = f16(val)   (v transposed;  A=Wv,     B=x)
template <int MODE>
__global__ __launch_bounds__(256) void proj_gemm(
    const half_t* __restrict__ A, const half_t* __restrict__ Bm,
    const float* __restrict__ bias, half_t* __restrict__ out) {
  __shared__ half_t At[2 * 4 * 2048];
  __shared__ half_t Bt[2 * 8192];
  const int tid = threadIdx.x;
  const int lane = tid & 63, wv = tid >> 6;
  const int g = lane >> 4, li = lane & 15;
  const int wm = wv >> 1, wn = wv & 1;
  const int M0 = blockIdx.x * 128, N0 = blockIdx.y * 128;

  const f32x4 kZero = {0.f, 0.f, 0.f, 0.f};
  f32x4 acc[4][4];
#pragma unroll
  for (int i = 0; i < 4; ++i)
#pragma unroll
    for (int j = 0; j < 4; ++j) acc[i][j] = kZero;

  gemm_core<8, 512, 512, 4>((const char*)(A + (size_t)M0 * 512),
                            (const char*)(Bm + (size_t)N0 * 512), At, Bt, tid, acc);

  if (MODE == 2) {
#pragma unroll
    for (int i = 0; i < 4; ++i) {
      int trow = M0 + wm * 64 + i * 16 + 4 * g;
#pragma unroll
      for (int j = 0; j < 4; ++j) {
        int m = N0 + wn * 64 + j * 16 + li;
        float bs = bias[m];
#pragma unroll
        for (int r = 0; r < 4; ++r) {
          out[(size_t)(trow + r) * 512 + m] = (_Float16)(acc[i][j][r] + bs);
        }
      }
    }
  } else {
#pragma unroll
    for (int i = 0; i < 4; ++i) {
      int m0r = M0 + wm * 64 + i * 16 + 4 * g;
#pragma unroll
      for (int r = 0; r < 4; ++r) {
        int m = m0r + r;
        float bs = bias[m];
#pragma unroll
        for (int j = 0; j < 4; ++j) {
          int t = N0 + wn * 64 + j * 16 + li;
          out[(size_t)m * 16384 + t] = (_Float16)(acc[i][j][r] + bs);
        }
      }
    }
  }
}

// ---- S-GEMM (M=64): S[b][cc][d] = q[b,co+cc] . k[b,d], fp32 out -------------
// grid 2048 linear, batch->XCD affine: b = id&7; idx = id>>3 (0..255):
// M0 = (idx & 15)*64 (c-tile), N0 = (idx >> 4)*128 (d-tile).
__global__ __launch_bounds__(256) void s_gemm(
    const half_t* __restrict__ q, const half_t* __restrict__ k,
    float* __restrict__ S, int co) {
  __shared__ half_t At[2 * 2 * 2048];
  __shared__ half_t Bt[2 * 8192];
  const int tid = threadIdx.x;
  const int lane = tid & 63, wv = tid >> 6;
  const int g = lane >> 4, li = lane & 15;
  const int wm = wv >> 1, wn = wv & 1;
  const int id = blockIdx.x;
  const int b = id & 7;
  const int idx = id >> 3;
  const int M0 = (idx & 15) * 64;       // local c within chunk
  const int N0 = (idx >> 4) * 128;      // d

  const f32x4 kZero = {0.f, 0.f, 0.f, 0.f};
  f32x4 acc[2][4];
#pragma unroll
  for (int i = 0; i < 2; ++i)
#pragma unroll
    for (int j = 0; j < 4; ++j) acc[i][j] = kZero;

  gemm_core<8, 512, 512, 2>(
      (const char*)(q + (size_t)(b * 2048 + co + M0) * 512),
      (const char*)(k + (size_t)(b * 2048 + N0) * 512), At, Bt, tid, acc);

  float* Sb = S + (size_t)(b * 1024 + M0) * 2048 + N0;
#pragma unroll
  for (int i = 0; i < 2; ++i) {
#pragma unroll
    for (int j = 0; j < 4; ++j) {
#pragma unroll
      for (int r = 0; r < 4; ++r) {
        Sb[(size_t)(wm * 32 + i * 16 + 4 * g + r) * 2048 + wn * 64 + j * 16 + li] =
            acc[i][j][r];
      }
    }
  }
}

// ---- row softmax: wave per row; P = exp(s - max) fp16 written IN-PLACE ------
__global__ __launch_bounds__(256) void softmax_rows(
    float* __restrict__ S, float* __restrict__ lbuf) {
  const int rr = blockIdx.x * 4 + (threadIdx.x >> 6);
  const int lane = threadIdx.x & 63;
  float* Srow = S + (size_t)rr * 2048;

  f32x4 v[8];
#pragma unroll
  for (int it = 0; it < 8; ++it) v[it] = *(const f32x4*)&Srow[lane * 4 + it * 256];

  float mx = -3e38f;
#pragma unroll
  for (int it = 0; it < 8; ++it)
    mx = fmaxf(mx, fmaxf(fmaxf(v[it][0], v[it][1]), fmaxf(v[it][2], v[it][3])));
  mx = fmaxf(mx, __shfl_xor(mx, 1));
  mx = fmaxf(mx, __shfl_xor(mx, 2));
  mx = fmaxf(mx, __shfl_xor(mx, 4));
  mx = fmaxf(mx, __shfl_xor(mx, 8));
  mx = fmaxf(mx, __shfl_xor(mx, 16));
  mx = fmaxf(mx, __shfl_xor(mx, 32));

  float sum = 0.f;
  half4 h[8];
#pragma unroll
  for (int it = 0; it < 8; ++it) {
#pragma unroll
    for (int j = 0; j < 4; ++j) {
      float p = __expf(v[it][j] - mx);
      sum += p;
      h[it][j] = (_Float16)p;
    }
  }
  sum += __shfl_xor(sum, 1);
  sum += __shfl_xor(sum, 2);
  sum += __shfl_xor(sum, 4);
  sum += __shfl_xor(sum, 8);
  sum += __shfl_xor(sum, 16);
  sum += __shfl_xor(sum, 32);

  half_t* P = (half_t*)S;
#pragma unroll
  for (int it = 0; it < 8; ++it)
    *(half4*)&P[(size_t)rr * 4096 + lane * 4 + it * 256] = h[it];
  if (lane == 0) lbuf[rr] = sum;
}

// ---- PV-GEMM (M=64): out[b][n][co+cc] = (P[b,cc] . V^T[n]) / (l*sqrt512) ----
// grid 512 linear, batch->XCD affine: b = id&7; idx = id>>3 (0..63):
// M0 = (idx >> 2)*64 (c-tile), N0 = (idx & 3)*128 (n-tile).
__global__ __launch_bounds__(256) void pv_gemm(
    const half_t* __restrict__ P, const half_t* __restrict__ vt,
    const float* __restrict__ lbuf, float* __restrict__ outp, int co) {
  __shared__ half_t At[2 * 2 * 2048];
  __shared__ half_t Bt[2 * 8192];
  const int tid = threadIdx.x;
  const int lane = tid & 63, wv = tid >> 6;
  const int g = lane >> 4, li = lane & 15;
  const int wm = wv >> 1, wn = wv & 1;
  const int id = blockIdx.x;
  const int b = id & 7;
  const int idx = id >> 3;
  const int M0 = (idx >> 2) * 64;       // local c within chunk
  const int N0 = (idx & 3) * 128;       // n

  const f32x4 kZero = {0.f, 0.f, 0.f, 0.f};
  f32x4 acc[2][4];
#pragma unroll
  for (int i = 0; i < 2; ++i)
#pragma unroll
    for (int j = 0; j < 4; ++j) acc[i][j] = kZero;

  gemm_core<32, 4096, 16384, 2>(
      (const char*)(P + (size_t)(b * 1024 + M0) * 4096),
      (const char*)(vt + (size_t)N0 * 16384 + (size_t)b * 2048), At, Bt, tid, acc);

  // epilogue: scale by 1/(l*sqrt(512)), transposed scatter out[b][n][c]
#pragma unroll
  for (int i = 0; i < 2; ++i) {
    int c0r = M0 + wm * 32 + i * 16 + 4 * g;   // + r (local c)
    float inv[4];
#pragma unroll
    for (int r = 0; r < 4; ++r)
      inv[r] = 1.0f / (lbuf[b * 1024 + c0r + r] * 22.62741699796952f);
#pragma unroll
    for (int j = 0; j < 4; ++j) {
      int n = N0 + wn * 64 + j * 16 + li;
      float* ob = outp + (size_t)b * 1048576 + (size_t)n * 2048 + co + c0r;
#pragma unroll
      for (int r = 0; r < 4; ++r) {
        ob[r] = acc[i][j][r] * inv[r];
      }
    }
  }
}

// ---------------------------------------------------------------------------
extern "C" void kernel_launch(void* const* d_in, const int* in_sizes, int n_in,
                              void* d_out, int out_size, void* d_ws, size_t ws_size,
                              hipStream_t stream) {
  const float* x  = (const float*)d_in[0];
  const float* Wq = (const float*)d_in[1];
  const float* bq = (const float*)d_in[2];
  const float* Wk = (const float*)d_in[3];
  const float* bk = (const float*)d_in[4];
  const float* Wv = (const float*)d_in[5];
  const float* bv = (const float*)d_in[6];

  // workspace layout (phases overlap in the S-region):
  half_t* qsb  = (half_t*)d_ws;                     // [16384][512]   16 MB
  half_t* ksb  = qsb + (size_t)16384 * 512;         // [16384][512]   16 MB
  half_t* vtb  = ksb + (size_t)16384 * 512;         // [512][16384]   16 MB
  half_t* xh   = vtb + (size_t)512 * 16384;         // [16384][512]   16 MB (proj phase)
  half_t* wqh  = xh  + (size_t)16384 * 512;         // [512][512]     0.5 MB
  half_t* wkh  = wqh + (size_t)512 * 512;
  half_t* wvh  = wkh + (size_t)512 * 512;
  float*  Sbuf = (float*)xh;                        // [8192][2048] fp32 67 MB (attn phase)
  float*  lbuf = (float*)(((char*)d_ws) + (size_t)117 * 1024 * 1024);  // [8192]

  cast_f16<<<dim3(16384 * 512 / 4 / 256), 256, 0, stream>>>(x, xh, 16384 * 512 / 4);
  cast_f16<<<dim3(512 * 512 / 4 / 256), 256, 0, stream>>>(Wq, wqh, 512 * 512 / 4);
  cast_f16<<<dim3(512 * 512 / 4 / 256), 256, 0, stream>>>(Wk, wkh, 512 * 512 / 4);
  cast_f16<<<dim3(512 * 512 / 4 / 256), 256, 0, stream>>>(Wv, wvh, 512 * 512 / 4);

  proj_gemm<2><<<dim3(128, 4), 256, 0, stream>>>(xh, wqh, bq, qsb);
  proj_gemm<2><<<dim3(128, 4), 256, 0, stream>>>(xh, wkh, bk, ksb);
  proj_gemm<1><<<dim3(4, 128), 256, 0, stream>>>(wvh, xh, bv, vtb);

  for (int chunk = 0; chunk < 2; ++chunk) {
    const int co = chunk * 1024;
    s_gemm<<<dim3(2048), 256, 0, stream>>>(qsb, ksb, Sbuf, co);
    softmax_rows<<<dim3(2048), 256, 0, stream>>>(Sbuf, lbuf);
    pv_gemm<<<dim3(512), 256, 0, stream>>>((const half_t*)Sbuf, vtb, lbuf,
                                           (float*)d_out, co);
  }
}